// Round 1
// baseline (356.797 us; speedup 1.0000x reference)
//
#include <hip/hip_runtime.h>
#include <hip/hip_bf16.h>
#include <stdint.h>

#define M_DIM 4096
#define N_DIM 4096
#define K_DIM 4096
#define NGROUPS (N_DIM * K_DIM / 8)   // 2,097,152 groups of 8 weights

typedef __attribute__((ext_vector_type(4))) float f32x4;
typedef __attribute__((ext_vector_type(8))) short bf16x8;
typedef __attribute__((ext_vector_type(4))) int   i32x4;

// fp32 -> bf16 round-to-nearest-even
__device__ __forceinline__ ushort f2bf(float f) {
  union { float f; uint32_t u; } v; v.f = f;
  uint32_t r = v.u + 0x7FFFu + ((v.u >> 16) & 1u);
  return (ushort)(r >> 16);
}

// ---------------- pre-pass 1: dequant 4-bit W -> bf16 [N][K] ----------------
// one thread per group of 8 weights: 16B packed load, 16B bf16 store
__global__ void k_dequant_w(const int* __restrict__ wp, const float* __restrict__ wsc,
                            const float* __restrict__ wbs, ushort* __restrict__ W) {
  const int g = blockIdx.x * 256 + threadIdx.x;
  i32x4 p = *(const i32x4*)(wp + (size_t)g * 4);
  const float s = wsc[g];
  const float b = wbs[g];
  bf16x8 o;
#pragma unroll
  for (int j = 0; j < 4; ++j) {
    const float lo = (float)(p[j] & 15)        * s + b;  // even position
    const float hi = (float)((p[j] >> 4) & 15) * s + b;  // odd position
    o[2 * j]     = (short)f2bf(lo);
    o[2 * j + 1] = (short)f2bf(hi);
  }
  *(bf16x8*)(W + (size_t)g * 8) = o;  // flat offset g*8 == row-major [N][K]
}

// ---------------- pre-pass 2: cast x fp32 -> bf16 [M][K] ----------------
__global__ void k_cvt_x(const float* __restrict__ x, ushort* __restrict__ X) {
  const int t = blockIdx.x * 256 + threadIdx.x;
  f32x4 a = *(const f32x4*)(x + (size_t)t * 8);
  f32x4 b = *(const f32x4*)(x + (size_t)t * 8 + 4);
  bf16x8 o;
#pragma unroll
  for (int j = 0; j < 4; ++j) {
    o[j]     = (short)f2bf(a[j]);
    o[4 + j] = (short)f2bf(b[j]);
  }
  *(bf16x8*)(X + (size_t)t * 8) = o;
}

// ---------------- main: bf16 GEMM C = A * B^T + bias (m97 structure) --------
// A [M][K] bf16 row-major, B [N][K] bf16 row-major. 128x128 tile, BK=64,
// 4 waves (2x2), each wave 64x64 = 4x4 frags of 16x16x32 MFMA.
__global__ __launch_bounds__(256) void k_gemm_bt(
    const ushort* __restrict__ A, const ushort* __restrict__ B,
    const float* __restrict__ bias, float* __restrict__ C) {
  __shared__ ushort sA[128 * 64];
  __shared__ ushort sB[128 * 64];
  const int tid  = threadIdx.x;
  const int wave = tid >> 6;
  const int lane = tid & 63;
  const int bm = blockIdx.x >> 5;   // 32x32 block grid
  const int bn = blockIdx.x & 31;
  const int wm = (wave >> 1) * 64;
  const int wn = (wave & 1) * 64;

  const ushort* Ab = A + (size_t)bm * 128 * K_DIM;
  const ushort* Bb = B + (size_t)bn * 128 * K_DIM;

  f32x4 acc[4][4] = {};

  const int lrow = lane & 15;        // fragment row within 16
  const int lk   = (lane >> 4) * 8;  // k sub-offset within 32

  for (int kk = 0; kk < K_DIM; kk += 64) {
    // stage A tile 128x64 bf16 (16KB): 4 issues x 256 lanes x 16B
#pragma unroll
    for (int i = 0; i < 4; ++i) {
      const int flat = i * 256 + tid;  // 16B chunk index; row=flat>>3, kc=flat&7
      __builtin_amdgcn_global_load_lds(
          (const __attribute__((address_space(1))) void*)
              (Ab + (size_t)(flat >> 3) * K_DIM + kk + (flat & 7) * 8),
          (__attribute__((address_space(3))) void*)(sA + (i * 256 + wave * 64) * 8),
          16, 0, 0);
    }
#pragma unroll
    for (int i = 0; i < 4; ++i) {
      const int flat = i * 256 + tid;
      __builtin_amdgcn_global_load_lds(
          (const __attribute__((address_space(1))) void*)
              (Bb + (size_t)(flat >> 3) * K_DIM + kk + (flat & 7) * 8),
          (__attribute__((address_space(3))) void*)(sB + (i * 256 + wave * 64) * 8),
          16, 0, 0);
    }
    __syncthreads();  // drains vmcnt(0) before barrier (compiler-emitted)

#pragma unroll
    for (int kc = 0; kc < 2; ++kc) {
      bf16x8 af[4], bq[4];
#pragma unroll
      for (int mi = 0; mi < 4; ++mi)
        af[mi] = *(const bf16x8*)(sA + (wm + mi * 16 + lrow) * 64 + kc * 32 + lk);
#pragma unroll
      for (int ni = 0; ni < 4; ++ni)
        bq[ni] = *(const bf16x8*)(sB + (wn + ni * 16 + lrow) * 64 + kc * 32 + lk);
#pragma unroll
      for (int mi = 0; mi < 4; ++mi)
#pragma unroll
        for (int ni = 0; ni < 4; ++ni)
          acc[mi][ni] = __builtin_amdgcn_mfma_f32_16x16x32_bf16(
              af[mi], bq[ni], acc[mi][ni], 0, 0, 0);
    }
    __syncthreads();
  }

  // epilogue: C/D layout col=lane&15, row=(lane>>4)*4+reg  (m89-verified)
  const int fr = lane & 15;
  const int fq = lane >> 4;
  const int growbase = bm * 128 + wm;
  const int gcolbase = bn * 128 + wn;
#pragma unroll
  for (int ni = 0; ni < 4; ++ni) {
    const int col = gcolbase + ni * 16 + fr;
    const float bv = bias[col];
#pragma unroll
    for (int mi = 0; mi < 4; ++mi) {
      float* cp = C + (size_t)(growbase + mi * 16 + fq * 4) * N_DIM + col;
#pragma unroll
      for (int r = 0; r < 4; ++r)
        cp[(size_t)r * N_DIM] = acc[mi][ni][r] + bv;
    }
  }
}

// ---------------- fallback (only if ws too small): fused naive fp32 ---------
__global__ void k_fallback(const float* __restrict__ x, const int* __restrict__ wp,
                           const float* __restrict__ wsc, const float* __restrict__ wbs,
                           const float* __restrict__ bias, float* __restrict__ y) {
  const int m = blockIdx.x;
  const int n = blockIdx.y * 256 + threadIdx.x;
  const float* xr = x + (size_t)m * K_DIM;
  const int gbase = n * (K_DIM / 8);
  float acc = 0.f;
  for (int g = 0; g < K_DIM / 8; ++g) {
    i32x4 p = *(const i32x4*)(wp + (size_t)(gbase + g) * 4);
    const float s = wsc[gbase + g];
    const float b = wbs[gbase + g];
    const float* xk = xr + g * 8;
#pragma unroll
    for (int j = 0; j < 4; ++j) {
      acc += ((float)(p[j] & 15)        * s + b) * xk[2 * j];
      acc += ((float)((p[j] >> 4) & 15) * s + b) * xk[2 * j + 1];
    }
  }
  y[(size_t)m * N_DIM + n] = acc + bias[n];
}

extern "C" void kernel_launch(void* const* d_in, const int* in_sizes, int n_in,
                              void* d_out, int out_size, void* d_ws, size_t ws_size,
                              hipStream_t stream) {
  const float* x    = (const float*)d_in[0];
  const int*   wp   = (const int*)d_in[1];
  const float* wsc  = (const float*)d_in[2];
  const float* wbs  = (const float*)d_in[3];
  const float* bias = (const float*)d_in[4];
  float* y = (float*)d_out;

  const size_t wbytes = (size_t)N_DIM * K_DIM * sizeof(ushort);  // 32 MB
  const size_t xbytes = (size_t)M_DIM * K_DIM * sizeof(ushort);  // 32 MB

  if (ws_size >= wbytes + xbytes) {
    ushort* Wbf = (ushort*)d_ws;
    ushort* Xbf = (ushort*)((char*)d_ws + wbytes);
    k_dequant_w<<<NGROUPS / 256, 256, 0, stream>>>(wp, wsc, wbs, Wbf);
    k_cvt_x<<<(M_DIM * K_DIM / 8) / 256, 256, 0, stream>>>(x, Xbf);
    k_gemm_bt<<<32 * 32, 256, 0, stream>>>(Xbf, Wbf, bias, y);
  } else {
    k_fallback<<<dim3(M_DIM, N_DIM / 256), 256, 0, stream>>>(x, wp, wsc, wbs, bias, y);
  }
}

// Round 4
// 297.359 us; speedup vs baseline: 1.1999x; 1.1999x over previous
//
#include <hip/hip_runtime.h>
#include <hip/hip_bf16.h>
#include <stdint.h>

#define M_DIM 4096
#define N_DIM 4096
#define K_DIM 4096
#define NGROUPS (N_DIM * K_DIM / 8)

typedef __attribute__((ext_vector_type(4))) float f32x4;
typedef __attribute__((ext_vector_type(8))) short bf16x8;
typedef __attribute__((ext_vector_type(4))) int   i32x4;

__device__ __forceinline__ ushort f2bf(float f) {
  union { float f; uint32_t u; } v; v.f = f;
  uint32_t r = v.u + 0x7FFFu + ((v.u >> 16) & 1u);
  return (ushort)(r >> 16);
}

// ---------------- pre-pass 1: dequant 4-bit W -> bf16 [N][K] ----------------
__global__ void k_dequant_w(const int* __restrict__ wp, const float* __restrict__ wsc,
                            const float* __restrict__ wbs, ushort* __restrict__ W) {
  const int g = blockIdx.x * 256 + threadIdx.x;
  i32x4 p = *(const i32x4*)(wp + (size_t)g * 4);
  const float s = wsc[g];
  const float b = wbs[g];
  bf16x8 o;
#pragma unroll
  for (int j = 0; j < 4; ++j) {
    const float lo = (float)(p[j] & 15)        * s + b;
    const float hi = (float)((p[j] >> 4) & 15) * s + b;
    o[2 * j]     = (short)f2bf(lo);
    o[2 * j + 1] = (short)f2bf(hi);
  }
  *(bf16x8*)(W + (size_t)g * 8) = o;
}

// ---------------- pre-pass 2: cast x fp32 -> bf16 [M][K] ----------------
__global__ void k_cvt_x(const float* __restrict__ x, ushort* __restrict__ X) {
  const int t = blockIdx.x * 256 + threadIdx.x;
  f32x4 a = *(const f32x4*)(x + (size_t)t * 8);
  f32x4 b = *(const f32x4*)(x + (size_t)t * 8 + 4);
  bf16x8 o;
#pragma unroll
  for (int j = 0; j < 4; ++j) {
    o[j]     = (short)f2bf(a[j]);
    o[4 + j] = (short)f2bf(b[j]);
  }
  *(bf16x8*)(X + (size_t)t * 8) = o;
}

// ---------------- main: 256x256 tile, BK=64, 8 waves, 4-phase pipeline ------
// LDS: 2 buffers x (A 256x64 + B 256x64) bf16 = 128 KB. Tile-granular dbuf:
// prefetch tile t+1 issued at phases 0-1 of tile t; single __syncthreads
// (vmcnt0 drain ~3 phases after issue) per tile is the only correctness sync.
// Swizzle: 16B-chunk involution c ^= (row&7), applied on global SOURCE of
// global_load_lds (LDS dest linear) and on ds_read addresses.

#define GLD(src, dst) __builtin_amdgcn_global_load_lds(                        \
    (const __attribute__((address_space(1))) void*)(src),                      \
    (__attribute__((address_space(3))) void*)(dst), 16, 0, 0)

__global__ __launch_bounds__(512, 2) void k_gemm_8ph(
    const ushort* __restrict__ A, const ushort* __restrict__ B,
    const float* __restrict__ bias, float* __restrict__ C) {
  __shared__ ushort sA[2][256 * 64];
  __shared__ ushort sB[2][256 * 64];
  const int tid  = threadIdx.x;
  const int lane = tid & 63;
  const int wid  = tid >> 6;
  const int wr   = wid >> 2;   // 0..1  (M)
  const int wc   = wid & 3;    // 0..3  (N)
  const int bm = blockIdx.x >> 4;
  const int bn = blockIdx.x & 15;

  const ushort* Ab = A + (size_t)bm * 256 * K_DIM;
  const ushort* Bb = B + (size_t)bn * 256 * K_DIM;

  // staging geometry: per thread, 4 chunks of 16B per operand per tile.
  // flat chunk = j*512 + tid; row = flat>>3 (= j*64 + tid>>3), col-chunk = tid&7.
  // source col-chunk pre-swizzled so that linear LDS ends up XOR-swizzled.
  // Wave-uniform LDS chunk base for wave wid: chunks j*512 + wid*64 + lane
  // land at ushort offset (j*512 + wid*64)*8 + lane*8 (HW adds lane*16B).
  const int srow = tid >> 3;
  const int scc  = (tid & 7) ^ ((tid >> 3) & 7);
  const int dofs = (tid >> 6) * 64 * 8;  // = wid*512 ushorts  (R2 bug: was wid*4096)

  // fragment read geometry (swizzled)
  const int l15   = lane & 15;
  const int kx    = (lane >> 4) * 8;
  const int xsw   = (lane & 7) << 3;
  const int kidx0 = (0 * 32 + kx) ^ xsw;
  const int kidx1 = (1 * 32 + kx) ^ xsw;
  const int abase = (wr * 128 + l15) * 64;
  const int bbase = (wc * 64 + l15) * 64;

  f32x4 acc[8][4] = {};

#define STAGE_A(buf, kko)                                                      \
  _Pragma("unroll") for (int j = 0; j < 4; ++j)                                \
      GLD(Ab + (size_t)(j * 64 + srow) * K_DIM + (kko) + scc * 8,              \
          &sA[buf][j * 4096 + dofs]);
#define STAGE_B(buf, kko)                                                      \
  _Pragma("unroll") for (int j = 0; j < 4; ++j)                                \
      GLD(Bb + (size_t)(j * 64 + srow) * K_DIM + (kko) + scc * 8,              \
          &sB[buf][j * 4096 + dofs]);

  // prologue: stage tile 0 into buf 0
  STAGE_A(0, 0);
  STAGE_B(0, 0);
  __syncthreads();

  for (int t = 0; t < 64; ++t) {
    const int b  = t & 1;
    const int kk = t * 64;
    const ushort* sAb = sA[b];
    const ushort* sBb = sB[b];
    bf16x8 af[4][2], bf0[2][2], bf1[2][2];

    // ---- phase 0: read A-half0 + B-pair0; issue A prefetch; MFMA Q(0,0)
#pragma unroll
    for (int m = 0; m < 4; ++m) {
      af[m][0] = *(const bf16x8*)(sAb + abase + m * 1024 + kidx0);
      af[m][1] = *(const bf16x8*)(sAb + abase + m * 1024 + kidx1);
    }
#pragma unroll
    for (int n = 0; n < 2; ++n) {
      bf0[n][0] = *(const bf16x8*)(sBb + bbase + n * 1024 + kidx0);
      bf0[n][1] = *(const bf16x8*)(sBb + bbase + n * 1024 + kidx1);
    }
    if (t < 63) { STAGE_A(b ^ 1, kk + 64); }
    __builtin_amdgcn_s_barrier();
    __builtin_amdgcn_s_setprio(1);
#pragma unroll
    for (int m = 0; m < 4; ++m)
#pragma unroll
      for (int n = 0; n < 2; ++n)
#pragma unroll
        for (int kc = 0; kc < 2; ++kc)
          acc[m][n] = __builtin_amdgcn_mfma_f32_16x16x32_bf16(
              af[m][kc], bf0[n][kc], acc[m][n], 0, 0, 0);
    __builtin_amdgcn_s_setprio(0);
    __builtin_amdgcn_s_barrier();

    // ---- phase 1: read B-pair1; issue B prefetch; MFMA Q(0,1)
#pragma unroll
    for (int n = 0; n < 2; ++n) {
      bf1[n][0] = *(const bf16x8*)(sBb + bbase + (2 + n) * 1024 + kidx0);
      bf1[n][1] = *(const bf16x8*)(sBb + bbase + (2 + n) * 1024 + kidx1);
    }
    if (t < 63) { STAGE_B(b ^ 1, kk + 64); }
    __builtin_amdgcn_s_barrier();
    __builtin_amdgcn_s_setprio(1);
#pragma unroll
    for (int m = 0; m < 4; ++m)
#pragma unroll
      for (int n = 0; n < 2; ++n)
#pragma unroll
        for (int kc = 0; kc < 2; ++kc)
          acc[m][2 + n] = __builtin_amdgcn_mfma_f32_16x16x32_bf16(
              af[m][kc], bf1[n][kc], acc[m][2 + n], 0, 0, 0);
    __builtin_amdgcn_s_setprio(0);
    __builtin_amdgcn_s_barrier();

    // ---- phase 2: read A-half1 (overwrite af); MFMA Q(1,1)
#pragma unroll
    for (int m = 0; m < 4; ++m) {
      af[m][0] = *(const bf16x8*)(sAb + abase + (4 + m) * 1024 + kidx0);
      af[m][1] = *(const bf16x8*)(sAb + abase + (4 + m) * 1024 + kidx1);
    }
    __builtin_amdgcn_s_barrier();
    __builtin_amdgcn_s_setprio(1);
#pragma unroll
    for (int m = 0; m < 4; ++m)
#pragma unroll
      for (int n = 0; n < 2; ++n)
#pragma unroll
        for (int kc = 0; kc < 2; ++kc)
          acc[4 + m][2 + n] = __builtin_amdgcn_mfma_f32_16x16x32_bf16(
              af[m][kc], bf1[n][kc], acc[4 + m][2 + n], 0, 0, 0);
    __builtin_amdgcn_s_setprio(0);
    __builtin_amdgcn_s_barrier();

    // ---- phase 3: MFMA Q(1,0)  (bf0 kept live from phase 0, no reads)
    __builtin_amdgcn_s_setprio(1);
#pragma unroll
    for (int m = 0; m < 4; ++m)
#pragma unroll
      for (int n = 0; n < 2; ++n)
#pragma unroll
        for (int kc = 0; kc < 2; ++kc)
          acc[4 + m][n] = __builtin_amdgcn_mfma_f32_16x16x32_bf16(
              af[m][kc], bf0[n][kc], acc[4 + m][n], 0, 0, 0);
    __builtin_amdgcn_s_setprio(0);

    // tile boundary: drains vmcnt(0) (prefetch issued ~3 phases ago) + barrier
    __syncthreads();
  }

  // epilogue: C/D layout col=lane&15, row=(lane>>4)*4+reg (m89-verified)
  const int fr = lane & 15;
  const int fq = lane >> 4;
  const int growbase = bm * 256 + wr * 128;
  const int gcolbase = bn * 256 + wc * 64;
#pragma unroll
  for (int ni = 0; ni < 4; ++ni) {
    const int col = gcolbase + ni * 16 + fr;
    const float bv = bias[col];
#pragma unroll
    for (int mi = 0; mi < 8; ++mi) {
      float* cp = C + (size_t)(growbase + mi * 16 + fq * 4) * N_DIM + col;
#pragma unroll
      for (int r = 0; r < 4; ++r)
        cp[(size_t)r * N_DIM] = acc[mi][ni][r] + bv;
    }
  }
}

// ---------------- fallback (only if ws too small): fused naive fp32 ---------
__global__ void k_fallback(const float* __restrict__ x, const int* __restrict__ wp,
                           const float* __restrict__ wsc, const float* __restrict__ wbs,
                           const float* __restrict__ bias, float* __restrict__ y) {
  const int m = blockIdx.x;
  const int n = blockIdx.y * 256 + threadIdx.x;
  const float* xr = x + (size_t)m * K_DIM;
  const int gbase = n * (K_DIM / 8);
  float acc = 0.f;
  for (int g = 0; g < K_DIM / 8; ++g) {
    i32x4 p = *(const i32x4*)(wp + (size_t)(gbase + g) * 4);
    const float s = wsc[gbase + g];
    const float b = wbs[gbase + g];
    const float* xk = xr + g * 8;
#pragma unroll
    for (int j = 0; j < 4; ++j) {
      acc += ((float)(p[j] & 15)        * s + b) * xk[2 * j];
      acc += ((float)((p[j] >> 4) & 15) * s + b) * xk[2 * j + 1];
    }
  }
  y[(size_t)m * N_DIM + n] = acc + bias[n];
}

extern "C" void kernel_launch(void* const* d_in, const int* in_sizes, int n_in,
                              void* d_out, int out_size, void* d_ws, size_t ws_size,
                              hipStream_t stream) {
  const float* x    = (const float*)d_in[0];
  const int*   wp   = (const int*)d_in[1];
  const float* wsc  = (const float*)d_in[2];
  const float* wbs  = (const float*)d_in[3];
  const float* bias = (const float*)d_in[4];
  float* y = (float*)d_out;

  const size_t wbytes = (size_t)N_DIM * K_DIM * sizeof(ushort);
  const size_t xbytes = (size_t)M_DIM * K_DIM * sizeof(ushort);

  if (ws_size >= wbytes + xbytes) {
    ushort* Wbf = (ushort*)d_ws;
    ushort* Xbf = (ushort*)((char*)d_ws + wbytes);
    k_dequant_w<<<NGROUPS / 256, 256, 0, stream>>>(wp, wsc, wbs, Wbf);
    k_cvt_x<<<(M_DIM * K_DIM / 8) / 256, 256, 0, stream>>>(x, Xbf);
    k_gemm_8ph<<<16 * 16, 512, 0, stream>>>(Xbf, Wbf, bias, y);
  } else {
    k_fallback<<<dim3(M_DIM, N_DIM / 256), 256, 0, stream>>>(x, wp, wsc, wbs, bias, y);
  }
}